// Round 10
// baseline (151.305 us; speedup 1.0000x reference)
//
#include <hip/hip_runtime.h>
#include <math.h>

typedef unsigned int uint;
typedef unsigned long ulong;
typedef unsigned char uchar;
typedef __attribute__((ext_vector_type(4))) float f32x4;

// Problem constants
#define BB  16384
#define DD  64
#define NT_ 128
#define NZ_ 2048
#define NJ_ 2049   // NZ+1

// workspace layout (float offsets)
#define BIAS_OFF 0         // fp32 [64]
#define SCS_OFF  64        // float4 [2048] = {cc, inv, q, 0}
#define CZ8A_OFF 8256      // fp8 cz k0 [NZ][32]
#define CZ8B_OFF 24640     // fp8 cz k1 [NZ][32]
#define WZ8A_OFF 41024     // fp8 WzT k0 [NZ][32]
#define WZ8B_OFF 57408     // fp8 WzT k1 [NZ][32]
#define WZBP_OFF 73792     // fp8 Wz packed [64 chunks][64 d][32 c]
#define PART_OFF 106560    // fp32 partials [4][64][NJ_] = 524544
// end 631104 floats ~= 2.5 MB

// ---------------- fp8 e4m3 (OCP) conversion helpers ----------------
#if __has_builtin(__builtin_amdgcn_cvt_pk_fp8_f32)
__device__ __forceinline__ uint pk4_fp8(float a, float b, float c, float d) {
  int v = __builtin_amdgcn_cvt_pk_fp8_f32(a, b, 0, false);
  v = __builtin_amdgcn_cvt_pk_fp8_f32(c, d, v, true);
  return (uint)v;
}
__device__ __forceinline__ uchar f8_1(float x) {
  return (uchar)(__builtin_amdgcn_cvt_pk_fp8_f32(x, x, 0, false) & 0xFF);
}
#else
__device__ __forceinline__ uint sw_f8(float x) {
  uint u = __float_as_uint(x);
  uint s = (u >> 24) & 0x80u;
  float ax = __uint_as_float(u & 0x7FFFFFFFu);
  if (!(ax >= 0.015625f)) return s;          // flush tiny / NaN -> signed zero
  if (ax >= 448.f) return s | 0x7Eu;
  uint q = __float_as_uint(ax);
  q += 0x7FFFFu + ((q >> 20) & 1u);          // RNE at mantissa bit 20
  uint e = (q >> 23) - 120u;                 // rebias (127 -> 7)
  return s | ((e & 0xFu) << 3) | ((q >> 20) & 7u);
}
__device__ __forceinline__ uchar f8_1(float x) { return (uchar)sw_f8(x); }
__device__ __forceinline__ uint pk4_fp8(float a, float b, float c, float d) {
  return sw_f8(a) | (sw_f8(b) << 8) | (sw_f8(c) << 16) | (sw_f8(d) << 24);
}
#endif

// ---------------------------------------------------------------------------
// Kernel 1 (stage 1): split-K partial sums of W_t = einsum('dij,i->dj').
__global__ __launch_bounds__(256) void k_wt1(
    const float* __restrict__ t, const float* __restrict__ ct,
    const float* __restrict__ lst, const float* __restrict__ W,
    float* __restrict__ part)   // [4][64][NJ_]
{
  __shared__ float ph[32];
  int tx = threadIdx.x;
  int d  = blockIdx.y;
  int ic = blockIdx.z;
  if (tx < 32) {
    int i = ic * 32 + tx;
    float r = fabsf(t[0] - ct[i]) * __expf(-lst[i]);
    ph[tx] = __expf(-r * r);
  }
  __syncthreads();
  int j = blockIdx.x * 256 + tx;
  if (j >= NJ_) return;
  const float* Wp = W + (size_t)d * NT_ * NJ_ + (size_t)(ic * 32) * NJ_ + j;
  float acc = 0.f;
#pragma unroll
  for (int k = 0; k < 32; ++k) acc += Wp[(size_t)k * NJ_] * ph[k];
  part[((size_t)ic * 64 + d) * NJ_ + j] = acc;
}

// ---------------------------------------------------------------------------
// Kernel 2 (stage 2): 256 blocks x 256 thr, 8 centres/block.
__global__ __launch_bounds__(256) void k_prep2(
    const float* __restrict__ part, const float* __restrict__ cz,
    const float* __restrict__ lsz,
    float* __restrict__ bias, float4* __restrict__ scs,
    uchar* __restrict__ cz8a, uchar* __restrict__ cz8b,
    uchar* __restrict__ wz8a, uchar* __restrict__ wz8b,
    uchar* __restrict__ wzbp8)
{
  __shared__ float wt[64][9];   // [d][c_local]
  int tid = threadIdx.x;
  int cb0 = blockIdx.x * 8;
#pragma unroll
  for (int h = 0; h < 2; ++h) {
    int f = h * 256 + tid;      // 512 = 64 d x 8 c
    int d = f >> 3, c = f & 7;
    size_t idx = (size_t)d * NJ_ + cb0 + c;
    float s = part[idx] + part[(size_t)64 * NJ_ + idx]
            + part[(size_t)128 * NJ_ + idx] + part[(size_t)192 * NJ_ + idx];
    wt[d][c] = s;
    int cg = cb0 + c;
    wzbp8[((size_t)(cg >> 5) * 64 + d) * 32 + (cg & 31)] = f8_1(s);
  }
  if (blockIdx.x == 0 && tid < 64) {
    size_t idx = (size_t)tid * NJ_ + 2048;
    bias[tid] = part[idx] + part[(size_t)64 * NJ_ + idx]
              + part[(size_t)128 * NJ_ + idx] + part[(size_t)192 * NJ_ + idx];
  }
  __syncthreads();
  int cl = tid >> 5;            // centre within block 0..7
  int k  = tid & 31;            // 0..31
  int c  = cb0 + cl;
  float cv0 = cz[(size_t)c * DD + k];
  float cv1 = cz[(size_t)c * DD + 32 + k];
  cz8a[(size_t)c * 32 + k] = f8_1(cv0);
  cz8b[(size_t)c * 32 + k] = f8_1(cv1);
  float w0 = wt[k][cl], w1 = wt[32 + k][cl];
  wz8a[(size_t)c * 32 + k] = f8_1(w0);
  wz8b[(size_t)c * 32 + k] = f8_1(w1);
  float ca = cv0 * cv0 + cv1 * cv1;
  float qa = w0 * cv0 + w1 * cv1;
  qa += __shfl_xor(qa, 1);  ca += __shfl_xor(ca, 1);
  qa += __shfl_xor(qa, 2);  ca += __shfl_xor(ca, 2);
  qa += __shfl_xor(qa, 4);  ca += __shfl_xor(ca, 4);
  qa += __shfl_xor(qa, 8);  ca += __shfl_xor(ca, 8);
  qa += __shfl_xor(qa, 16); ca += __shfl_xor(ca, 16);
  if (k == 0) scs[c] = make_float4(ca, __expf(-2.f * lsz[c]), qa, 0.f);
}

// ---------------------------------------------------------------------------
// Main fused MFMA kernel — fp8, software-pipelined, BM=16, grid 1024.
// Block: 256 thr = 4 waves = 4-way c-split; 1 M-tile (16 rows) per block.
// 4 blocks/CU resident = 16 waves/CU. z converted fp32->fp8 in prologue.
#define PH_LD 40   // bytes per phi row (32 + 8 pad)

__global__ __launch_bounds__(256) void k_fused(
    const float* __restrict__ z,     // [BB][64] fp32
    const uchar* __restrict__ cz8a, const uchar* __restrict__ cz8b,
    const uchar* __restrict__ wz8a, const uchar* __restrict__ wz8b,
    const uchar* __restrict__ wzbp8,
    const float4* __restrict__ scs, const float* __restrict__ bias,
    float* __restrict__ out)
{
  __shared__ char smem[5376];    // phi [2][4][16][PH_LD] fp8 (5120B) OR eps [16][68] f32
  __shared__ float dlr[4][16];
  uchar* phs = (uchar*)smem;
  float* eps = (float*)smem;

  int tid  = threadIdx.x;
  int ws   = tid >> 6;           // wave = c-split group 0..3
  int lane = tid & 63;
  int lrow = lane & 15, quad = lane >> 4;
  int b0 = blockIdx.x * 16;

  // A-fragments from fp32 z, packed to fp8 in-register; exact zz alongside
  long az[2];
  float zzr[4];
  {
    const float* zr = z + (size_t)(b0 + lrow) * DD + quad * 8;
    float4 u0 = *(const float4*)(zr);
    float4 u1 = *(const float4*)(zr + 4);
    float4 u2 = *(const float4*)(zr + 32);
    float4 u3 = *(const float4*)(zr + 36);
    uint l0 = pk4_fp8(u0.x, u0.y, u0.z, u0.w);
    uint h0 = pk4_fp8(u1.x, u1.y, u1.z, u1.w);
    uint l1 = pk4_fp8(u2.x, u2.y, u2.z, u2.w);
    uint h1 = pk4_fp8(u3.x, u3.y, u3.z, u3.w);
    az[0] = (long)((ulong)l0 | ((ulong)h0 << 32));
    az[1] = (long)((ulong)l1 | ((ulong)h1 << 32));
    float p = u0.x*u0.x + u0.y*u0.y + u0.z*u0.z + u0.w*u0.w
            + u1.x*u1.x + u1.y*u1.y + u1.z*u1.z + u1.w*u1.w
            + u2.x*u2.x + u2.y*u2.y + u2.z*u2.z + u2.w*u2.w
            + u3.x*u3.x + u3.y*u3.y + u3.z*u3.z + u3.w*u3.w;
    p += __shfl_xor(p, 16);
    p += __shfl_xor(p, 32);      // lane holds zz[row b0+lrow]
#pragma unroll
    for (int i = 0; i < 4; ++i) zzr[i] = __shfl(p, quad * 4 + i);
  }

  f32x4 acc[4];
#pragma unroll
  for (int nt = 0; nt < 4; ++nt) acc[nt] = (f32x4){0.f, 0.f, 0.f, 0.f};
  float dl[4] = {0.f, 0.f, 0.f, 0.f};

  const f32x4 zero = (f32x4){0.f, 0.f, 0.f, 0.f};
  int cbase = ws * 512;
  int pbase = ws * 16 * PH_LD;   // within one parity bank

  // ---- register double-buffered prefetch state ----
  long Abc0[2][2], Abc1[2][2], Abw0[2][2], Abw1[2][2], Abb[2][4];
  float4 Asc[2][2];
#define LOADB(PAR, C0)                                                         \
  do {                                                                         \
    int c0_ = (C0);                                                            \
    _Pragma("unroll")                                                          \
    for (int nt = 0; nt < 2; ++nt) {                                           \
      int cg_ = c0_ + nt * 16 + lrow;                                          \
      size_t ro_ = (size_t)cg_ * 32 + quad * 8;                                \
      Abc0[PAR][nt] = *(const long*)(cz8a + ro_);                              \
      Abc1[PAR][nt] = *(const long*)(cz8b + ro_);                              \
      Abw0[PAR][nt] = *(const long*)(wz8a + ro_);                              \
      Abw1[PAR][nt] = *(const long*)(wz8b + ro_);                              \
      Asc[PAR][nt]  = scs[cg_];                                                \
    }                                                                          \
    size_t cb_ = (size_t)(c0_ >> 5) * 64 * 32;                                 \
    _Pragma("unroll")                                                          \
    for (int nt = 0; nt < 4; ++nt)                                             \
      Abb[PAR][nt] =                                                           \
          *(const long*)(wzbp8 + cb_ + (size_t)(nt * 16 + lrow) * 32 + quad * 8); \
  } while (0)

  LOADB(0, cbase);
#pragma unroll 2
  for (int it = 0; it < 16; ++it) {
    int par = it & 1;
    // prefetch next chunk (wraps on last iter -> always in-bounds)
    LOADB(par ^ 1, cbase + ((it + 1) & 15) * 32);

    int pb = par * (4 * 16 * PH_LD) + pbase;
    // ---- GEMM1 + elementwise (2 n-tiles of 16 centres) ----
#pragma unroll
    for (int nt = 0; nt < 2; ++nt) {
      float4 sc = Asc[par][nt];       // {cc, inv, q, 0}
      f32x4 d1 = __builtin_amdgcn_mfma_f32_16x16x32_fp8_fp8(az[0], Abc0[par][nt], zero, 0, 0, 0);
      d1       = __builtin_amdgcn_mfma_f32_16x16x32_fp8_fp8(az[1], Abc1[par][nt], d1,   0, 0, 0);
      f32x4 d2 = __builtin_amdgcn_mfma_f32_16x16x32_fp8_fp8(az[0], Abw0[par][nt], zero, 0, 0, 0);
      d2       = __builtin_amdgcn_mfma_f32_16x16x32_fp8_fp8(az[1], Abw1[par][nt], d2,   0, 0, 0);
#pragma unroll
      for (int i = 0; i < 4; ++i) {
        float s = zzr[i] + sc.x - 2.f * d1[i];
        s = fmaxf(s, 0.f);
        float p = __expf(-s * sc.y);
        dl[i] += p * sc.y * (d2[i] - sc.z);
        phs[pb + (quad * 4 + i) * PH_LD + nt * 16 + lrow] = f8_1(p);
      }
    }
    // ---- GEMM2: dz += phi @ Wz ----
    long ap = *(const long*)&phs[pb + lrow * PH_LD + quad * 8];
#pragma unroll
    for (int nt = 0; nt < 4; ++nt)
      acc[nt] = __builtin_amdgcn_mfma_f32_16x16x32_fp8_fp8(ap, Abb[par][nt], acc[nt], 0, 0, 0);
  }
#undef LOADB

  // ---- dl partials (dlr not unioned; safe before combine barriers) ----
#pragma unroll
  for (int i = 0; i < 4; ++i) {
    float v = dl[i];
    v += __shfl_xor(v, 1);
    v += __shfl_xor(v, 2);
    v += __shfl_xor(v, 4);
    v += __shfl_xor(v, 8);
    if (lrow == 0) dlr[ws][quad * 4 + i] = v;
  }

  // ---- dz combine across the 4 c-split waves (eps reuses phi LDS) ----
  for (int s = 0; s < 4; ++s) {
    __syncthreads();
    if (ws == s) {
#pragma unroll
      for (int nt = 0; nt < 4; ++nt)
#pragma unroll
        for (int i = 0; i < 4; ++i) {
          int r = quad * 4 + i;
          int d = nt * 16 + lrow;
          if (s == 0) eps[r * 68 + d] = acc[nt][i];
          else        eps[r * 68 + d] += acc[nt][i];
        }
    }
  }
  __syncthreads();

  // ---- outputs ----
  {
    int r = tid >> 4, d0 = (tid & 15) * 4;   // 256 thr x 4 floats = 16x64
    float4 e  = *(const float4*)&eps[r * 68 + d0];
    float4 bv = *(const float4*)&bias[d0];
    float4 o;
    o.x = e.x + bv.x; o.y = e.y + bv.y; o.z = e.z + bv.z; o.w = e.w + bv.w;
    *(float4*)&out[(size_t)(b0 + r) * DD + d0] = o;
  }
  if (tid < 16) {
    float s = dlr[0][tid] + dlr[1][tid] + dlr[2][tid] + dlr[3][tid];
    out[(size_t)BB * DD + b0 + tid] = 2.f * s;
  }
}

// ---------------------------------------------------------------------------
extern "C" void kernel_launch(void* const* d_in, const int* in_sizes, int n_in,
                              void* d_out, int out_size, void* d_ws, size_t ws_size,
                              hipStream_t stream)
{
  const float* t   = (const float*)d_in[0];
  const float* z   = (const float*)d_in[1];
  // d_in[2] = logp_z (unused)
  const float* cz  = (const float*)d_in[3];
  const float* lsz = (const float*)d_in[4];
  const float* ct  = (const float*)d_in[5];
  const float* lst = (const float*)d_in[6];
  const float* W   = (const float*)d_in[7];
  float* out = (float*)d_out;
  float* ws  = (float*)d_ws;

  float*  bias = ws + BIAS_OFF;
  float4* scs  = (float4*)(ws + SCS_OFF);
  uchar*  cz8a = (uchar*)(ws + CZ8A_OFF);
  uchar*  cz8b = (uchar*)(ws + CZ8B_OFF);
  uchar*  wz8a = (uchar*)(ws + WZ8A_OFF);
  uchar*  wz8b = (uchar*)(ws + WZ8B_OFF);
  uchar*  wzbp8 = (uchar*)(ws + WZBP_OFF);
  float*  part = ws + PART_OFF;

  k_wt1<<<dim3(9, 64, 4), 256, 0, stream>>>(t, ct, lst, W, part);
  k_prep2<<<dim3(256), 256, 0, stream>>>(part, cz, lsz, bias, scs,
                                         cz8a, cz8b, wz8a, wz8b, wzbp8);
  k_fused<<<dim3(BB / 16), 256, 0, stream>>>(z, cz8a, cz8b, wz8a, wz8b,
                                             wzbp8, scs, bias, out);
}